// Round 1
// baseline (2325.259 us; speedup 1.0000x reference)
//
#include <hip/hip_runtime.h>

// Problem constants (from reference)
constexpr int B_   = 16;
constexpr int CIN  = 128;
constexpr int H_   = 224;
constexpr int W_   = 224;
constexpr int COUT = 256;
constexpr int KH   = 3;
constexpr int KW   = 3;
constexpr int SH   = 2;   // stride h
constexpr int SW   = 3;   // stride w
constexpr int PAD  = 1;
constexpr int HOUT = (H_ + 2 * PAD - KH) / SH + 1;   // 112
constexpr int WOUT = (W_ + 2 * PAD - KW) / SW + 1;   // 75
constexpr int SPATIAL = HOUT * WOUT;                  // 8400

constexpr int CO_T = 8;          // output channels per thread
constexpr int BLOCK = 256;

__global__ __launch_bounds__(BLOCK) void conv_direct(
    const float* __restrict__ x, const float* __restrict__ wgt,
    const float* __restrict__ bias, float* __restrict__ out) {

  const int cog = blockIdx.x;                    // 0..COUT/CO_T-1 (fastest: L2 reuse of x tile)
  const int sp  = blockIdx.y * BLOCK + threadIdx.x;
  const int b   = blockIdx.z;
  const int co0 = cog * CO_T;

  const bool active = sp < SPATIAL;
  const int sp_c = active ? sp : 0;
  const int oh = sp_c / WOUT;
  const int ow = sp_c % WOUT;
  const int ih0 = oh * SH - PAD;
  const int iw0 = ow * SW - PAD;

  float acc[CO_T];
#pragma unroll
  for (int t = 0; t < CO_T; ++t) acc[t] = 0.f;

  const float* xb = x + (size_t)b * CIN * H_ * W_;
  const float* wp = wgt + (size_t)co0 * CIN * KH * KW;

  for (int ci = 0; ci < CIN; ++ci) {
    const float* xc = xb + (size_t)ci * H_ * W_;

    // gather the 3x3 input patch (zero-padded at borders)
    float xv[9];
#pragma unroll
    for (int kh = 0; kh < KH; ++kh) {
      const int ih = ih0 + kh;
      const bool rowok = (unsigned)ih < (unsigned)H_;
#pragma unroll
      for (int kw = 0; kw < KW; ++kw) {
        const int iw = iw0 + kw;
        const bool ok = rowok && ((unsigned)iw < (unsigned)W_) && active;
        xv[kh * KW + kw] = ok ? xc[ih * W_ + iw] : 0.f;
      }
    }

    // 8 output channels reuse the same patch; weights are block-uniform (scalar loads)
#pragma unroll
    for (int t = 0; t < CO_T; ++t) {
      const float* wt = wp + ((size_t)t * CIN + ci) * (KH * KW);
#pragma unroll
      for (int k = 0; k < KH * KW; ++k)
        acc[t] = fmaf(xv[k], wt[k], acc[t]);
    }
  }

  if (!active) return;

#pragma unroll
  for (int t = 0; t < CO_T; ++t) {
    out[(((size_t)b * COUT + (co0 + t)) * (size_t)SPATIAL) + sp] = acc[t] + bias[co0 + t];
  }
}

extern "C" void kernel_launch(void* const* d_in, const int* in_sizes, int n_in,
                              void* d_out, int out_size, void* d_ws, size_t ws_size,
                              hipStream_t stream) {
  const float* x    = (const float*)d_in[0];
  const float* wgt  = (const float*)d_in[1];
  const float* bias = (const float*)d_in[2];
  float* out        = (float*)d_out;

  dim3 grid(COUT / CO_T, (SPATIAL + BLOCK - 1) / BLOCK, B_);
  dim3 block(BLOCK);
  conv_direct<<<grid, block, 0, stream>>>(x, wgt, bias, out);
}

// Round 2
// 452.585 us; speedup vs baseline: 5.1377x; 5.1377x over previous
//
#include <hip/hip_runtime.h>
#include <cstdint>

// Problem constants
constexpr int B_   = 16;
constexpr int CIN  = 128;
constexpr int H_   = 224;
constexpr int W_   = 224;
constexpr int COUT = 256;
constexpr int HOUT = 112;
constexpr int WOUT = 75;

// Tiling
constexpr int OWP  = 80;            // padded ow per output row
constexpr int BM   = 160;           // 2 output rows x 80
constexpr int BN   = 128;           // out-channels per block
constexpr int CI_SC = 16;           // input channels per super-chunk
constexpr int KSC  = CI_SC * 9;     // 144 k per super-chunk
constexpr int NSC  = CIN / CI_SC;   // 8 super-chunks
constexpr int THREADS = 256;        // 4 waves; each wave owns 32 co, all 160 m

typedef float f32x16 __attribute__((ext_vector_type(16)));
typedef short short8 __attribute__((ext_vector_type(8)));   // 8 bf16 (guide-verified operand type)

struct U64x2 { unsigned long long lo, hi; };

// fp32 -> bf16 round-to-nearest-even (inputs are finite)
__device__ inline unsigned short f2bf(float f) {
  unsigned u = __builtin_bit_cast(unsigned, f);
  return (unsigned short)((u + 0x7FFFu + ((u >> 16) & 1u)) >> 16);
}

__global__ __launch_bounds__(THREADS, 3) void conv_mfma(
    const float* __restrict__ x, const float* __restrict__ wgt,
    const float* __restrict__ bias, float* __restrict__ out) {

  // LDS A-tile: [KSC][BM] bf16 in [4k x 16m] subtiles:
  // byte(k,m) = ((k>>2)*10 + (m>>4))*128 + (k&3)*32 + (m&15)*2
  __shared__ __align__(16) unsigned char smem[KSC * BM * 2];

  // XCD-chunked bijective swizzle: 1792 blocks = 8 XCDs * 224
  int Lid   = (blockIdx.x & 7) * 224 + (blockIdx.x >> 3);
  int coBlk = Lid & 1;               // co-pair adjacent within an XCD chunk
  int t     = Lid >> 1;
  int ohp   = t % 56;
  int b     = t / 56;
  int oh_base = ohp * 2;

  const int tid  = threadIdx.x;
  const int lane = tid & 63;
  const int wv   = tid >> 6;

  const float* xb = x + (size_t)b * CIN * H_ * W_;
  const int co_lane = coBlk * BN + wv * 32 + (lane & 31);
  const float* wrow = wgt + (size_t)co_lane * (CIN * 9);

  const unsigned sbase = (unsigned)(uintptr_t)&smem[0];
  // per-lane tr-read base: lane-group g4=(lane>>4) targets subtile
  // (kk = 2*(lane>>5), mm = (lane>>4)&1), lane-linear 8B within the 128B region
  const unsigned abase = sbase
      + ((2u * (lane >> 5)) * 10u + ((lane >> 4) & 1u)) * 128u
      + (lane & 15) * 8u;

  f32x16 acc[5];
#pragma unroll
  for (int mf = 0; mf < 5; ++mf)
#pragma unroll
    for (int i = 0; i < 16; ++i) acc[mf][i] = 0.f;

  for (int sc = 0; sc < NSC; ++sc) {
    if (sc) __syncthreads();

    // ---- stage super-chunk: 16 ci x {2 output rows x 3 kh} x 19 ow-groups ----
    for (int it = tid; it < CI_SC * 3 * 2 * 19; it += THREADS) {
      int ci  = it & 15;
      int t2  = it >> 4;
      int g   = t2 % 19;
      int t3  = t2 / 19;
      int kh  = t3 % 3;
      int ohl = t3 / 3;

      int ih = 2 * (oh_base + ohl) - 1 + kh;
      bool rowok = (unsigned)ih < (unsigned)H_;
      const float* row = xb + ((size_t)(sc * CI_SC + ci) * H_ + (rowok ? ih : 0)) * W_;
      int iw0 = 12 * g - 1;

      unsigned short hb[12];
#pragma unroll
      for (int e = 0; e < 12; ++e) {
        int iw = iw0 + e;
        bool ok = rowok && ((unsigned)iw < (unsigned)W_);
        int iwc = iw < 0 ? 0 : (iw > W_ - 1 ? W_ - 1 : iw);
        float v = row[iwc];
        hb[e] = f2bf(ok ? v : 0.f);
      }
      // de-interleave: element e -> (kw = e%3, ow = 4g + e/3); write b64 per kw
#pragma unroll
      for (int kw = 0; kw < 3; ++kw) {
        unsigned lo = (unsigned)hb[kw]     | ((unsigned)hb[kw + 3] << 16);
        unsigned hi = (unsigned)hb[kw + 6] | ((unsigned)hb[kw + 9] << 16);
        int k = ci * 9 + kh * 3 + kw;
        int m = ohl * OWP + 4 * g;
        unsigned byte = (unsigned)(((k >> 2) * 10 + (m >> 4)) * 128 + (k & 3) * 32 + (m & 15) * 2);
        *reinterpret_cast<uint2*>(&smem[byte]) = make_uint2(lo, hi);
      }
    }
    __syncthreads();

    // ---- compute: 9 MFMA k-chunks of K=16 ----
#pragma unroll
    for (int kc = 0; kc < 9; ++kc) {
      // B fragment straight from global weights (k = ci*9+kh*3+kw matches W layout)
      int kg = sc * KSC + kc * 16 + ((lane >> 5) * 8);
      const float4* wp4 = reinterpret_cast<const float4*>(wrow + kg);
      float4 f0 = wp4[0], f1 = wp4[1];
      short8 bfrag;
      bfrag[0] = (short)f2bf(f0.x); bfrag[1] = (short)f2bf(f0.y);
      bfrag[2] = (short)f2bf(f0.z); bfrag[3] = (short)f2bf(f0.w);
      bfrag[4] = (short)f2bf(f1.x); bfrag[5] = (short)f2bf(f1.y);
      bfrag[6] = (short)f2bf(f1.z); bfrag[7] = (short)f2bf(f1.w);

      unsigned long long t1[5], t2[5];
#pragma unroll
      for (int mf = 0; mf < 5; ++mf) {
        unsigned a1 = abase + (unsigned)(kc * 5120 + mf * 256);
        asm volatile("ds_read_b64_tr_b16 %0, %1" : "=v"(t1[mf]) : "v"(a1));
        asm volatile("ds_read_b64_tr_b16 %0, %1 offset:1280" : "=v"(t2[mf]) : "v"(a1));
      }
      asm volatile("s_waitcnt lgkmcnt(0)" ::: "memory");
      __builtin_amdgcn_sched_barrier(0);

#pragma unroll
      for (int mf = 0; mf < 5; ++mf) {
        U64x2 u{t1[mf], t2[mf]};
        short8 afrag = __builtin_bit_cast(short8, u);
        acc[mf] = __builtin_amdgcn_mfma_f32_32x32x16_bf16(afrag, bfrag, acc[mf], 0, 0, 0);
      }
    }
  }

  // ---- epilogue: C layout col=lane&31 (co), row=(r&3)+8*(r>>2)+4*(lane>>5) (m) ----
  float bv = bias[co_lane];
#pragma unroll
  for (int mf = 0; mf < 5; ++mf) {
#pragma unroll
    for (int r = 0; r < 16; ++r) {
      int m   = mf * 32 + (r & 3) + 8 * (r >> 2) + 4 * (lane >> 5);
      int ohl = m >= OWP ? 1 : 0;
      int ow  = m - OWP * ohl;
      if (ow < WOUT) {
        int oh = oh_base + ohl;
        out[(((size_t)b * COUT + co_lane) * HOUT + oh) * WOUT + ow] = acc[mf][r] + bv;
      }
    }
  }
}

extern "C" void kernel_launch(void* const* d_in, const int* in_sizes, int n_in,
                              void* d_out, int out_size, void* d_ws, size_t ws_size,
                              hipStream_t stream) {
  const float* x    = (const float*)d_in[0];
  const float* wgt  = (const float*)d_in[1];
  const float* bias = (const float*)d_in[2];
  float* out        = (float*)d_out;

  dim3 grid(16 * 56 * 2);   // b * oh-pairs * co-halves, XCD-swizzled in-kernel
  dim3 block(THREADS);
  conv_mfma<<<grid, block, 0, stream>>>(x, wgt, bias, out);
}